// Round 1
// baseline (253.802 us; speedup 1.0000x reference)
//
#include <hip/hip_runtime.h>

// Problem constants
#define FMAPS 128     // feature maps
#define SEQL  512     // L
#define BATCH 64      // B
#define EMB   300     // embedding dim
#define EMBP  304     // padded embedding dim (multiple of 16B)
#define LPAD  514     // L + 2 (conv padding rows)
#define KTOT  912     // 3 * 304 contiguous-K GEMM depth
#define NROI  2048
#define FFDIM 512     // FEATURE_MAPS * POOLING_OUT
#define NCLS  8       // CLASSES + 1

static __device__ __forceinline__ float relu_(float x) { return x > 0.f ? x : 0.f; }

// ---------------------------------------------------------------------------
// 1. Pad sentence [B,512,300] -> Xp [B,514,304] (zeros in pad rows/cols).
//    After this, the (3,300) conv window for output l is 912 CONTIGUOUS floats
//    starting at Xp + (b*514 + l)*304.
// ---------------------------------------------------------------------------
__global__ void pad_kernel(const float* __restrict__ x, float* __restrict__ xp) {
    const int ROW4 = EMBP / 4;                 // 76 float4 per padded row
    int idx = blockIdx.x * blockDim.x + threadIdx.x;
    int total = BATCH * LPAD * ROW4;           // 2,500,096 (exact multiple of 256)
    if (idx >= total) return;
    int d4 = idx % ROW4;
    int t  = idx / ROW4;
    int r  = t % LPAD;                         // padded row
    int b  = t / LPAD;
    float4 v = make_float4(0.f, 0.f, 0.f, 0.f);
    if (r >= 1 && r <= SEQL && d4 < (EMB / 4)) {
        v = ((const float4*)(x + ((size_t)(b * SEQL + (r - 1))) * EMB))[d4];
    }
    ((float4*)xp)[idx] = v;
}

// ---------------------------------------------------------------------------
// 2. Weights [128][1][3][300] -> Wp [912][128] (B-transposed, zero-padded d>=300)
// ---------------------------------------------------------------------------
__global__ void wpad_kernel(const float* __restrict__ cw, float* __restrict__ wp) {
    int idx = blockIdx.x * blockDim.x + threadIdx.x;   // over 912*128
    if (idx >= KTOT * FMAPS) return;
    int f  = idx & (FMAPS - 1);
    int kk = idx >> 7;
    int k  = kk / EMBP;
    int d  = kk % EMBP;
    wp[idx] = (d < EMB) ? cw[f * 900 + k * 300 + d] : 0.f;
}

// ---------------------------------------------------------------------------
// 3a. Collapse FC chain: M[c][j] = sum_i cls_w[c][i] * fc1_w[i][j]   (8x512)
// ---------------------------------------------------------------------------
__global__ void collapse1_kernel(const float* __restrict__ cls_w,
                                 const float* __restrict__ fc1_w,
                                 float* __restrict__ M) {
    int idx = blockIdx.x * blockDim.x + threadIdx.x;   // 4096
    int c = idx >> 9;
    int j = idx & (FFDIM - 1);
    float s = 0.f;
    for (int i = 0; i < FFDIM; ++i)
        s = fmaf(cls_w[c * FFDIM + i], fc1_w[i * FFDIM + j], s);
    M[idx] = s;
}

// ---------------------------------------------------------------------------
// 3b. Fold repeat(4) into Mf[c][f] = sum_p M[c][4f+p]; b2 = cls_b + cls_w@fc1_b
// ---------------------------------------------------------------------------
__global__ void collapse2_kernel(const float* __restrict__ M,
                                 const float* __restrict__ cls_w,
                                 const float* __restrict__ fc1_b,
                                 const float* __restrict__ cls_b,
                                 float* __restrict__ Mf, float* __restrict__ b2) {
    int tid = threadIdx.x;                      // 1024 = 8*128
    int c = tid >> 7, j = tid & 127;
    const float* m = M + c * FFDIM + 4 * j;
    Mf[c * FMAPS + j] = m[0] + m[1] + m[2] + m[3];
    if (tid < NCLS) {
        float s = cls_b[tid];
        for (int i = 0; i < FFDIM; ++i)
            s = fmaf(cls_w[tid * FFDIM + i], fc1_b[i], s);
        b2[tid] = s;
    }
}

// ---------------------------------------------------------------------------
// 4. Conv-as-GEMM: feat[b][l][f] = relu( sum_{kk<912} Xp_row(b,l)[kk]*Wp[kk][f] + cb[f] )
//    BM=64 (l), BN=128 (all f), DK=48 (912 = 19*48), 256 threads, 4x8 per thread.
// ---------------------------------------------------------------------------
__global__ __launch_bounds__(256, 4) void conv_gemm(
    const float* __restrict__ xp, const float* __restrict__ wp,
    const float* __restrict__ cb, float* __restrict__ feat) {
    __shared__ float Asm[48][68];    // transposed A tile, padded to 68 for 16B-aligned rows
    __shared__ float Wsm[48][128];

    const int t  = threadIdx.x;
    const int tx = t & 15;           // f group: covers tx*4..+3 and tx*4+64..+67
    const int ty = t >> 4;           // m group: covers ty*4..+3
    const int b  = blockIdx.x >> 3;
    const int l0 = (blockIdx.x & 7) << 6;

    // A staging assignment: row am (0..63), 3 float4 slots at d = aj*4 + s*16
    const int am = t & 63;
    const int aj = t >> 6;
    const float* arow = xp + ((size_t)(b * LPAD + l0 + am)) * EMBP;
    // W staging assignment: 6 rows (wr + s*8) x float4 at f = wf
    const int wf = (t & 31) << 2;
    const int wr = t >> 5;

    float acc[4][8];
#pragma unroll
    for (int i = 0; i < 4; ++i)
#pragma unroll
        for (int j = 0; j < 8; ++j) acc[i][j] = 0.f;

    for (int kc = 0; kc < 19; ++kc) {
        const int d0 = kc * 48;
#pragma unroll
        for (int s = 0; s < 3; ++s) {
            int dd = (aj << 2) + s * 16;
            float4 v = *(const float4*)(arow + d0 + dd);
            Asm[dd + 0][am] = v.x;
            Asm[dd + 1][am] = v.y;
            Asm[dd + 2][am] = v.z;
            Asm[dd + 3][am] = v.w;
        }
#pragma unroll
        for (int s = 0; s < 6; ++s) {
            int rr = wr + (s << 3);
            *(float4*)&Wsm[rr][wf] = *(const float4*)(wp + (size_t)(d0 + rr) * FMAPS + wf);
        }
        __syncthreads();
#pragma unroll 8
        for (int d = 0; d < 48; ++d) {
            float4 a  = *(const float4*)&Asm[d][ty << 2];
            float4 b0 = *(const float4*)&Wsm[d][tx << 2];
            float4 b1 = *(const float4*)&Wsm[d][(tx << 2) + 64];
            float av[4] = {a.x, a.y, a.z, a.w};
            float bv[8] = {b0.x, b0.y, b0.z, b0.w, b1.x, b1.y, b1.z, b1.w};
#pragma unroll
            for (int i = 0; i < 4; ++i)
#pragma unroll
                for (int j = 0; j < 8; ++j)
                    acc[i][j] = fmaf(av[i], bv[j], acc[i][j]);
        }
        __syncthreads();
    }

    float4 cb0 = *(const float4*)(cb + (tx << 2));
    float4 cb1 = *(const float4*)(cb + (tx << 2) + 64);
#pragma unroll
    for (int i = 0; i < 4; ++i) {
        int l = l0 + (ty << 2) + i;
        float* orow = feat + ((size_t)(b * SEQL + l)) * FMAPS;
        float4 o0, o1;
        o0.x = relu_(acc[i][0] + cb0.x);
        o0.y = relu_(acc[i][1] + cb0.y);
        o0.z = relu_(acc[i][2] + cb0.z);
        o0.w = relu_(acc[i][3] + cb0.w);
        o1.x = relu_(acc[i][4] + cb1.x);
        o1.y = relu_(acc[i][5] + cb1.y);
        o1.z = relu_(acc[i][6] + cb1.z);
        o1.w = relu_(acc[i][7] + cb1.w);
        *(float4*)(orow + (tx << 2)) = o0;
        *(float4*)(orow + (tx << 2) + 64) = o1;
    }
}

// ---------------------------------------------------------------------------
// 5. ROI max-pool + collapsed FC. One wave per ROI; lane covers channels
//    {lane, lane+64}. 8 outputs via wave butterfly reductions.
// ---------------------------------------------------------------------------
__global__ __launch_bounds__(256) void roi_fc(
    const float* __restrict__ feat, const int* __restrict__ rois,
    const int* __restrict__ ridx, const float* __restrict__ mf,
    const float* __restrict__ b2, float* __restrict__ out) {
    const int w    = threadIdx.x >> 6;
    const int lane = threadIdx.x & 63;
    const int n    = blockIdx.x * 4 + w;       // grid 512 * 4 waves = 2048 exactly
    const int x1 = rois[n * 2 + 0];
    const int x2 = rois[n * 2 + 1];
    const int bi = ridx[n];
    const float* base = feat + ((size_t)bi * SEQL) * FMAPS;
    float m0 = -1e30f, m1 = -1e30f;
    for (int l = x1; l < x2; ++l) {
        const float* row = base + (size_t)l * FMAPS;
        m0 = fmaxf(m0, row[lane]);
        m1 = fmaxf(m1, row[lane + 64]);
    }
    float res[8];
#pragma unroll
    for (int c = 0; c < 8; ++c) {
        float p = m0 * mf[c * FMAPS + lane] + m1 * mf[c * FMAPS + 64 + lane];
#pragma unroll
        for (int off = 32; off; off >>= 1) p += __shfl_xor(p, off, 64);
        res[c] = p;
    }
    if (lane == 0) {
#pragma unroll
        for (int c = 0; c < 8; ++c) out[n * NCLS + c] = res[c] + b2[c];
    }
}

// ---------------------------------------------------------------------------
extern "C" void kernel_launch(void* const* d_in, const int* in_sizes, int n_in,
                              void* d_out, int out_size, void* d_ws, size_t ws_size,
                              hipStream_t stream) {
    const float* sentence = (const float*)d_in[0];
    const int*   rois     = (const int*)d_in[1];
    const int*   ridx     = (const int*)d_in[2];
    const float* conv_w   = (const float*)d_in[3];
    const float* conv_b   = (const float*)d_in[4];
    const float* fc1_w    = (const float*)d_in[5];
    const float* fc1_b    = (const float*)d_in[6];
    const float* cls_w    = (const float*)d_in[7];
    const float* cls_b    = (const float*)d_in[8];
    float* out = (float*)d_out;

    // workspace carve-up (floats). Total ~14.32M floats = ~57.3 MB.
    float* ws = (float*)d_ws;
    float* Xp = ws;                                         // 64*514*304 = 10,000,384
    float* Wp = Xp + (size_t)BATCH * LPAD * EMBP;           // 912*128   = 116,736
    float* Ft = Wp + (size_t)KTOT * FMAPS;                  // 64*512*128= 4,194,304
    float* Mm = Ft + (size_t)BATCH * SEQL * FMAPS;          // 8*512
    float* Mf = Mm + NCLS * FFDIM;                          // 8*128
    float* b2 = Mf + NCLS * FMAPS;                          // 8

    const int padTotal = BATCH * LPAD * (EMBP / 4);
    hipLaunchKernelGGL(pad_kernel, dim3((padTotal + 255) / 256), dim3(256), 0, stream,
                       sentence, Xp);
    hipLaunchKernelGGL(wpad_kernel, dim3((KTOT * FMAPS + 255) / 256), dim3(256), 0, stream,
                       conv_w, Wp);
    hipLaunchKernelGGL(collapse1_kernel, dim3(16), dim3(256), 0, stream,
                       cls_w, fc1_w, Mm);
    hipLaunchKernelGGL(collapse2_kernel, dim3(1), dim3(1024), 0, stream,
                       Mm, cls_w, fc1_b, cls_b, Mf, b2);
    hipLaunchKernelGGL(conv_gemm, dim3((BATCH * SEQL) / 64), dim3(256), 0, stream,
                       Xp, Wp, conv_b, Ft);
    hipLaunchKernelGGL(roi_fc, dim3(NROI / 4), dim3(256), 0, stream,
                       Ft, rois, ridx, Mf, b2, out);
}

// Round 3
// 140.074 us; speedup vs baseline: 1.8119x; 1.8119x over previous
//
#include <hip/hip_runtime.h>
#include <hip/hip_bf16.h>

// Problem constants
#define FMAPS 128     // feature maps
#define SEQL  512     // L
#define BATCH 64      // B
#define EMB   300     // embedding dim
#define EMBP  320     // padded embedding dim -> K = 3*320 = 960 = 30 * 32
#define LPAD  514     // L + 2 (conv padding rows)
#define NKC   30      // K-chunks of 32
#define NROI  2048
#define FFDIM 512     // FEATURE_MAPS * POOLING_OUT
#define NCLS  8       // CLASSES + 1

typedef short bf16x8 __attribute__((ext_vector_type(8)));   // 8 bf16 (4 VGPRs)
typedef float f32x4  __attribute__((ext_vector_type(4)));   // MFMA accumulator

static __device__ __forceinline__ float relu_(float x) { return x > 0.f ? x : 0.f; }
static __device__ __forceinline__ ushort bf16bits(float f) {
    __hip_bfloat16 h = __float2bfloat16(f);
    return *reinterpret_cast<ushort*>(&h);
}

// ---------------------------------------------------------------------------
// 1. Pad sentence [B,512,300] fp32 -> Xp [B,514,320] bf16 (zero pad rows/cols).
//    Conv window for output l = padded rows l..l+2, each 320 bf16.
// ---------------------------------------------------------------------------
__global__ void pad_bf16(const float* __restrict__ x, ushort* __restrict__ xp) {
    const int ROW4 = EMBP / 4;                   // 80 quads per padded row
    int idx = blockIdx.x * blockDim.x + threadIdx.x;
    int total = BATCH * LPAD * ROW4;             // 2,631,680
    if (idx >= total) return;
    int d4 = idx % ROW4;
    int t  = idx / ROW4;
    int r  = t % LPAD;
    int b  = t / LPAD;
    float4 v = make_float4(0.f, 0.f, 0.f, 0.f);
    if (r >= 1 && r <= SEQL && d4 < (EMB / 4)) {
        v = ((const float4*)(x + ((size_t)(b * SEQL + (r - 1))) * EMB))[d4];
    }
    ushort4 o;
    o.x = bf16bits(v.x); o.y = bf16bits(v.y); o.z = bf16bits(v.z); o.w = bf16bits(v.w);
    ((ushort4*)xp)[idx] = o;
}

// ---------------------------------------------------------------------------
// 2. Weights [128][1][3][300] fp32 -> WF fragment-major bf16:
//    WF[kc][nt][lane][j] = W[k = kc*32 + (lane>>4)*8 + j][f = nt*16 + (lane&15)]
//    where k -> (kr = k/320, d = k%320), zero for d >= 300.
// ---------------------------------------------------------------------------
__global__ void wpad_frag(const float* __restrict__ cw, ushort* __restrict__ wf) {
    int idx = blockIdx.x * blockDim.x + threadIdx.x;   // < 30*8*64*8 = 122880
    if (idx >= NKC * 8 * 64 * 8) return;
    int j    = idx & 7;
    int lane = (idx >> 3) & 63;
    int nt   = (idx >> 9) & 7;
    int kc   = idx >> 12;
    int f = nt * 16 + (lane & 15);
    int k = kc * 32 + (lane >> 4) * 8 + j;
    int kr = k / EMBP, d = k % EMBP;
    float v = (d < EMB) ? cw[f * 900 + kr * 300 + d] : 0.f;
    wf[idx] = bf16bits(v);
}

// ---------------------------------------------------------------------------
// 3a. prep: zero Mf[8][128], compute b2[c] = cls_b[c] + cls_w[c]·fc1_b  (512 thr)
// ---------------------------------------------------------------------------
__global__ void prep_kernel(const float* __restrict__ cls_w,
                            const float* __restrict__ fc1_b,
                            const float* __restrict__ cls_b,
                            float* __restrict__ Mf, float* __restrict__ b2) {
    int t = threadIdx.x;                  // 512
    Mf[t] = 0.f; Mf[t + 512] = 0.f;
    int c = t >> 6, lane = t & 63;
    float s = 0.f;
    for (int i = lane; i < FFDIM; i += 64)
        s = fmaf(cls_w[c * FFDIM + i], fc1_b[i], s);
#pragma unroll
    for (int off = 32; off; off >>= 1) s += __shfl_xor(s, off, 64);
    if (lane == 0) b2[c] = s + cls_b[c];
}

// ---------------------------------------------------------------------------
// 3b. collapse: Mf[c][g] += sum_{i in chunk} cls_w[c][i] * (sum_p fc1_w[i][4g+p])
//     grid 32 (i-chunks of 16), 256 threads: f=tid&127, c-half = tid>>7.
// ---------------------------------------------------------------------------
__global__ void collapse_kernel(const float* __restrict__ cls_w,
                                const float* __restrict__ fc1_w,
                                float* __restrict__ Mf) {
    int f  = threadIdx.x & 127;
    int c0 = (threadIdx.x >> 7) * 4;
    int i0 = blockIdx.x * 16;
    float acc[4] = {0.f, 0.f, 0.f, 0.f};
    for (int i = i0; i < i0 + 16; ++i) {
        float4 w4 = *(const float4*)(fc1_w + (size_t)i * FFDIM + f * 4);
        float ws = (w4.x + w4.y) + (w4.z + w4.w);
#pragma unroll
        for (int cc = 0; cc < 4; ++cc)
            acc[cc] = fmaf(cls_w[(c0 + cc) * FFDIM + i], ws, acc[cc]);
    }
#pragma unroll
    for (int cc = 0; cc < 4; ++cc)
        atomicAdd(Mf + (c0 + cc) * FMAPS + f, acc[cc]);
}

// ---------------------------------------------------------------------------
// 4. Conv as LDS-free MFMA GEMM.
//    C[M=32768][N=128] = A[M][K=960] * B[K][128], bf16 in, fp32 out + bias + relu.
//    Block: 256 thr = 4 waves (2M x 2N); wave tile 32x64 (M_rep=2, N_rep=4).
//    A-frag: lane holds Xp[b][row + kr][dc*32 + (lane>>4)*8 + 0..7], row = l + (lane&15)
//    B-frag: WF fragment-major, 1KB per wave-load, L2-hot.
// ---------------------------------------------------------------------------
__global__ __launch_bounds__(256, 2) void conv_mfma(
    const ushort* __restrict__ xp, const ushort* __restrict__ wf,
    const float* __restrict__ cb, float* __restrict__ feat) {
    const int t    = threadIdx.x;
    const int lane = t & 63;
    const int wid  = t >> 6;
    const int wm   = wid & 1;          // M half (32 rows)
    const int wn   = wid >> 1;         // N half (64 cols)
    const int b    = blockIdx.x >> 3;
    const int l0   = (blockIdx.x & 7) << 6;

    const int mrow = lane & 15;
    const int koct = lane >> 4;

    f32x4 acc[2][4] = {};

    // A base: padded row (l0 + wm*32 + mrow) + kr, k-offset koct*8
    const ushort* xrow0 = xp + ((size_t)b * LPAD + (l0 + wm * 32 + mrow)) * EMBP + koct * 8;
    const ushort* wlane = wf + (size_t)(wn * 4) * 512 + (size_t)lane * 8;

#pragma unroll
    for (int kr = 0; kr < 3; ++kr) {
        const ushort* xr = xrow0 + (size_t)kr * EMBP;
#pragma unroll
        for (int dc = 0; dc < 10; ++dc) {
            const int kc = kr * 10 + dc;
            bf16x8 a0 = *(const bf16x8*)(xr + dc * 32);
            bf16x8 a1 = *(const bf16x8*)(xr + 16 * EMBP + dc * 32);
            const ushort* wk = wlane + (size_t)kc * 4096;
            bf16x8 b0 = *(const bf16x8*)(wk);
            bf16x8 b1 = *(const bf16x8*)(wk + 512);
            bf16x8 b2v = *(const bf16x8*)(wk + 1024);
            bf16x8 b3 = *(const bf16x8*)(wk + 1536);
            acc[0][0] = __builtin_amdgcn_mfma_f32_16x16x32_bf16(a0, b0,  acc[0][0], 0, 0, 0);
            acc[0][1] = __builtin_amdgcn_mfma_f32_16x16x32_bf16(a0, b1,  acc[0][1], 0, 0, 0);
            acc[0][2] = __builtin_amdgcn_mfma_f32_16x16x32_bf16(a0, b2v, acc[0][2], 0, 0, 0);
            acc[0][3] = __builtin_amdgcn_mfma_f32_16x16x32_bf16(a0, b3,  acc[0][3], 0, 0, 0);
            acc[1][0] = __builtin_amdgcn_mfma_f32_16x16x32_bf16(a1, b0,  acc[1][0], 0, 0, 0);
            acc[1][1] = __builtin_amdgcn_mfma_f32_16x16x32_bf16(a1, b1,  acc[1][1], 0, 0, 0);
            acc[1][2] = __builtin_amdgcn_mfma_f32_16x16x32_bf16(a1, b2v, acc[1][2], 0, 0, 0);
            acc[1][3] = __builtin_amdgcn_mfma_f32_16x16x32_bf16(a1, b3,  acc[1][3], 0, 0, 0);
        }
    }

    // Epilogue: C/D layout col = lane&15, row = (lane>>4)*4 + r  [m91-verified]
#pragma unroll
    for (int n = 0; n < 4; ++n) {
        const int f = wn * 64 + n * 16 + mrow;   // (lane&15) -> N col
        const float bias = cb[f];
#pragma unroll
        for (int m = 0; m < 2; ++m) {
            const int lbase = l0 + wm * 32 + m * 16 + koct * 4;
#pragma unroll
            for (int r = 0; r < 4; ++r) {
                float v = acc[m][n][r] + bias;
                feat[((size_t)b * SEQL + (lbase + r)) * FMAPS + f] = relu_(v);
            }
        }
    }
}

// ---------------------------------------------------------------------------
// 5. ROI max-pool + collapsed FC. One wave per ROI; lane covers channels
//    {lane, lane+64}. 8 outputs via wave butterfly reductions.
// ---------------------------------------------------------------------------
__global__ __launch_bounds__(256) void roi_fc(
    const float* __restrict__ feat, const int* __restrict__ rois,
    const int* __restrict__ ridx, const float* __restrict__ mf,
    const float* __restrict__ b2, float* __restrict__ out) {
    const int w    = threadIdx.x >> 6;
    const int lane = threadIdx.x & 63;
    const int n    = blockIdx.x * 4 + w;       // grid 512 * 4 waves = 2048 exactly
    const int x1 = rois[n * 2 + 0];
    const int x2 = rois[n * 2 + 1];
    const int bi = ridx[n];
    const float* base = feat + ((size_t)bi * SEQL) * FMAPS;
    float m0 = -1e30f, m1 = -1e30f;
    for (int l = x1; l < x2; ++l) {
        const float* row = base + (size_t)l * FMAPS;
        m0 = fmaxf(m0, row[lane]);
        m1 = fmaxf(m1, row[lane + 64]);
    }
    float res[8];
#pragma unroll
    for (int c = 0; c < 8; ++c) {
        float p = m0 * mf[c * FMAPS + lane] + m1 * mf[c * FMAPS + 64 + lane];
#pragma unroll
        for (int off = 32; off; off >>= 1) p += __shfl_xor(p, off, 64);
        res[c] = p;
    }
    if (lane == 0) {
#pragma unroll
        for (int c = 0; c < 8; ++c) out[n * NCLS + c] = res[c] + b2[c];
    }
}

// ---------------------------------------------------------------------------
extern "C" void kernel_launch(void* const* d_in, const int* in_sizes, int n_in,
                              void* d_out, int out_size, void* d_ws, size_t ws_size,
                              hipStream_t stream) {
    const float* sentence = (const float*)d_in[0];
    const int*   rois     = (const int*)d_in[1];
    const int*   ridx     = (const int*)d_in[2];
    const float* conv_w   = (const float*)d_in[3];
    const float* conv_b   = (const float*)d_in[4];
    const float* fc1_w    = (const float*)d_in[5];
    const float* fc1_b    = (const float*)d_in[6];
    const float* cls_w    = (const float*)d_in[7];
    const float* cls_b    = (const float*)d_in[8];
    float* out = (float*)d_out;

    // workspace carve-up (bytes)
    char* ws = (char*)d_ws;
    ushort* Xp = (ushort*)ws;                                   // 64*514*320 bf16 = 21,053,440 B
    ushort* Wf = (ushort*)(ws + 21053440);                      // 122,880 bf16 = 245,760 B
    float*  Ft = (float*)(ws + 21053440 + 245760);              // 64*512*128 f32 = 16,777,216 B
    float*  Mf = (float*)(ws + 21053440 + 245760 + 16777216);   // 1024 f32
    float*  b2 = Mf + 1024;                                     // 8 f32

    const int padTotal = BATCH * LPAD * (EMBP / 4);
    hipLaunchKernelGGL(pad_bf16, dim3((padTotal + 255) / 256), dim3(256), 0, stream,
                       sentence, Xp);
    hipLaunchKernelGGL(wpad_frag, dim3((NKC * 8 * 64 * 8) / 256), dim3(256), 0, stream,
                       conv_w, Wf);
    hipLaunchKernelGGL(prep_kernel, dim3(1), dim3(512), 0, stream,
                       cls_w, fc1_b, cls_b, Mf, b2);
    hipLaunchKernelGGL(collapse_kernel, dim3(32), dim3(256), 0, stream,
                       cls_w, fc1_w, Mf);
    hipLaunchKernelGGL(conv_mfma, dim3((BATCH * SEQL) / 64), dim3(256), 0, stream,
                       Xp, Wf, conv_b, Ft);
    hipLaunchKernelGGL(roi_fc, dim3(NROI / 4), dim3(256), 0, stream,
                       Ft, rois, ridx, Mf, b2, out);
}